// Round 16
// baseline (24041.045 us; speedup 1.0000x reference)
//
#include <hip/hip_runtime.h>
#include <hip/hip_bf16.h>

#define B_ 256
#define S_ 2048
#define D_ 16
#define H_ 128

typedef unsigned int u32;
typedef _Float16 h2t __attribute__((ext_vector_type(2)));

// ---- output layout (flat f32): returns | volatility | hidden_h | hidden_c
#define RET0 ((size_t)0)
#define VOL0 ((size_t)524288)
#define HH0  ((size_t)1048576)
#define HC0  ((size_t)1114112)

__device__ __forceinline__ float fdot2(u32 a, u32 b, float c) {
    return __builtin_amdgcn_fdot2(__builtin_bit_cast(h2t, a),
                                  __builtin_bit_cast(h2t, b), c, false);
}
__device__ __forceinline__ u32 packh2(float a, float b) {
    h2t h; h[0] = (_Float16)a; h[1] = (_Float16)b;
    return __builtin_bit_cast(u32, h);
}
__device__ __forceinline__ float sigm(float x) {
    return __builtin_amdgcn_rcpf(1.f + __builtin_amdgcn_exp2f(-1.44269504f * x));
}
__device__ __forceinline__ float tanh_(float x) {
    return 2.f * __builtin_amdgcn_rcpf(1.f + __builtin_amdgcn_exp2f(-2.88539008f * x)) - 1.f;
}
__device__ __forceinline__ float softplus_(float x) {
    if (x > 20.f) return x;
    const float e = __builtin_amdgcn_exp2f(1.44269504f * x);
    return 0.69314718f * __builtin_amdgcn_logf(1.f + e);
}
// DPP lane^1 neighbor (quad_perm [1,0,3,2])
__device__ __forceinline__ float dnb1(float a) {
    return __builtin_bit_cast(float, __builtin_amdgcn_update_dpp(
        0, __builtin_bit_cast(int, a), 0xB1, 0xF, 0xF, true));
}

// ===================== fused layers 0+1 =====================================
// 1024 thr = 16 waves, 1 block/CU (grid = 256). waves_per_eu(4,4) pins the
// allocator at the 128-VGPR budget (round-15 default targeted 64 -> 14GB
// scratch-spill storm). tid<512: L1 (lag 2, h1 via 4-deep LDS ring);
// tid>=512: L0. One barrier per iteration.
__global__
__attribute__((amdgpu_waves_per_eu(4, 4)))
__launch_bounds__(1024, 1) void k_fused(
    const float* __restrict__ x,
    const float* __restrict__ Wih0, const float* __restrict__ Whh0,
    const float* __restrict__ bih0, const float* __restrict__ bhh0,
    const float* __restrict__ Wih1, const float* __restrict__ Whh1,
    const float* __restrict__ bih1, const float* __restrict__ bhh1,
    u32* __restrict__ hws, float* __restrict__ out)
{
    __shared__ u32 xp2[2][2048];          // 2 x 256-step x window (16KB)
    __shared__ float g0[2][4][128][4];    // l0 gate partials dbuf (16KB)
    __shared__ float g1[2][4][128][4];    // l1 gate partials dbuf (16KB)
    __shared__ u32 ring[4][64];           // h1 pair ring, 4-deep (1KB)
    __shared__ u32 hb0[8][16];            // l0 per-wave private h1 slices
    __shared__ u32 hb2[8][32];            // l1 per-wave private h2 slices
    __shared__ u32 och[2][2048];          // h2 32-step staging dbuf (16KB)

    const int tid = threadIdx.x, b = blockIdx.x;
    const bool isL1 = (tid < 512);
    const int ksl1 = tid >> 7, m1 = tid & 127;        // L1: A mapping
    const int wv1 = tid >> 6, j1 = tid & 63;
    const int unit1 = ((ksl1 & 1) << 6) + j1;         // L1: B unit (ksl1>=2)
    const int t0 = tid & 511;                         // L0 local id
    const int ksl0 = t0 >> 7, m0 = t0 & 127;
    const int wv0 = t0 >> 6, j0 = t0 & 63;
    const int unit0 = (ksl0 << 5) + (j0 & 31);

    u32 w[128];                                       // shared decl: L0 uses 72
    float bias[4];
    if (isL1) {
        const float* Wsel = (ksl1 < 2) ? Wih1 : Whh1;
        const int eb = (ksl1 & 1) * 64;
#pragma unroll
        for (int g = 0; g < 4; ++g) {
            const int row = g * H_ + m1;
            const float4* wr_ = (const float4*)(Wsel + row * H_ + eb);
#pragma unroll
            for (int q = 0; q < 16; ++q) {
                const float4 f = wr_[q];
                w[g * 32 + 2 * q]     = packh2(f.x, f.y);
                w[g * 32 + 2 * q + 1] = packh2(f.z, f.w);
            }
            bias[g] = bih1[g * H_ + unit1] + bhh1[g * H_ + unit1];
        }
    } else {
#pragma unroll
        for (int g = 0; g < 4; ++g) {
            const int row = g * H_ + m0;
            const float4 fx = *(const float4*)(Wih0 + row * D_ + ksl0 * 4);
            w[g * 18]     = packh2(fx.x, fx.y);
            w[g * 18 + 1] = packh2(fx.z, fx.w);
            const float4* whr = (const float4*)(Whh0 + row * H_ + ksl0 * 32);
#pragma unroll
            for (int q = 0; q < 8; ++q) {
                const float4 f = whr[q];
                w[g * 18 + 2 + 2 * q] = packh2(f.x, f.y);
                w[g * 18 + 3 + 2 * q] = packh2(f.z, f.w);
            }
            bias[g] = bih0[g * H_ + unit0] + bhh0[g * H_ + unit0];
        }
    }

    const float* xb = x + (size_t)b * S_ * D_;
    if (!isL1) {
#pragma unroll
        for (int k = 0; k < 2; ++k) {                 // stage x window 0
            const int i_ = t0 + k * 512;
            const float4 v = *(const float4*)(xb + i_ * 4);
            xp2[0][2 * i_]     = packh2(v.x, v.y);
            xp2[0][2 * i_ + 1] = packh2(v.z, v.w);
        }
    }
    if (tid < 128) ((u32*)hb0)[tid] = 0u;
    if (tid < 256) ((u32*)hb2)[tid] = 0u;
    float c = 0.f;
    u32* hbase = hws + (size_t)b * S_ * 64;
    __syncthreads();

    for (int i = 0; i <= S_ + 1; ++i) {
        // ================= phase A (dots) =================
        if (!isL1) {
            const int t = i;
            if (t < S_) {
                if ((t & 255) == 0 && t < S_ - 256) { // prefetch next x window
                    const int nw = (t >> 8) + 1;
#pragma unroll
                    for (int k = 0; k < 2; ++k) {
                        const int i_ = t0 + k * 512;
                        const float4 v = *(const float4*)(xb + (size_t)nw * 4096 + i_ * 4);
                        xp2[nw & 1][2 * i_]     = packh2(v.x, v.y);
                        xp2[nw & 1][2 * i_ + 1] = packh2(v.z, v.w);
                    }
                }
                const uint2 xv = *(const uint2*)&xp2[(t >> 8) & 1][(t & 255) * 8 + ksl0 * 2];
                const uint4* hq = (const uint4*)hb0[wv0];
                const uint4 h0 = hq[0], h1 = hq[1], h2 = hq[2], h3 = hq[3];
                float a0 = fdot2(xv.x, w[0], 0.f);  a0 = fdot2(xv.y, w[1], a0);
                float a1 = fdot2(xv.x, w[18], 0.f); a1 = fdot2(xv.y, w[19], a1);
                float a2 = fdot2(xv.x, w[36], 0.f); a2 = fdot2(xv.y, w[37], a2);
                float a3 = fdot2(xv.x, w[54], 0.f); a3 = fdot2(xv.y, w[55], a3);
#define DG(vv, p)                                                              \
                a0 = fdot2(vv, w[2 + (p)], a0);  a1 = fdot2(vv, w[20 + (p)], a1); \
                a2 = fdot2(vv, w[38 + (p)], a2); a3 = fdot2(vv, w[56 + (p)], a3);
                DG(h0.x, 0) DG(h0.y, 1) DG(h0.z, 2) DG(h0.w, 3)
                DG(h1.x, 4) DG(h1.y, 5) DG(h1.z, 6) DG(h1.w, 7)
                DG(h2.x, 8) DG(h2.y, 9) DG(h2.z, 10) DG(h2.w, 11)
                DG(h3.x, 12) DG(h3.y, 13) DG(h3.z, 14) DG(h3.w, 15)
#undef DG
                float4 part; part.x = a0; part.y = a1; part.z = a2; part.w = a3;
                *(float4*)&g0[i & 1][ksl0][m0][0] = part;
            }
        } else {
            const int u = i - 2;
            if (u >= 0) {
                uint4 v0, v1, v2, v3, v4, v5, v6, v7;
                if (ksl1 < 2) {                       // W_ih . h1[u] (ring)
                    const u32* src = &ring[u & 3][ksl1 * 32];
                    v0 = *(const uint4*)(src);      v1 = *(const uint4*)(src + 4);
                    v2 = *(const uint4*)(src + 8);  v3 = *(const uint4*)(src + 12);
                    v4 = *(const uint4*)(src + 16); v5 = *(const uint4*)(src + 20);
                    v6 = *(const uint4*)(src + 24); v7 = *(const uint4*)(src + 28);
                } else {                              // W_hh . h2[u-1] (private)
                    const u32* src = hb2[wv1];
                    v0 = *(const uint4*)(src);      v1 = *(const uint4*)(src + 4);
                    v2 = *(const uint4*)(src + 8);  v3 = *(const uint4*)(src + 12);
                    v4 = *(const uint4*)(src + 16); v5 = *(const uint4*)(src + 20);
                    v6 = *(const uint4*)(src + 24); v7 = *(const uint4*)(src + 28);
                }
                float a0 = 0.f, a1 = 0.f, a2 = 0.f, a3 = 0.f;
#define DQ(vv, q4)                                                             \
                a0 = fdot2(vv.x, w[q4], a0);      a0 = fdot2(vv.y, w[(q4)+1], a0); \
                a0 = fdot2(vv.z, w[(q4)+2], a0);  a0 = fdot2(vv.w, w[(q4)+3], a0); \
                a1 = fdot2(vv.x, w[32+(q4)], a1); a1 = fdot2(vv.y, w[33+(q4)], a1);\
                a1 = fdot2(vv.z, w[34+(q4)], a1); a1 = fdot2(vv.w, w[35+(q4)], a1);\
                a2 = fdot2(vv.x, w[64+(q4)], a2); a2 = fdot2(vv.y, w[65+(q4)], a2);\
                a2 = fdot2(vv.z, w[66+(q4)], a2); a2 = fdot2(vv.w, w[67+(q4)], a2);\
                a3 = fdot2(vv.x, w[96+(q4)], a3); a3 = fdot2(vv.y, w[97+(q4)], a3);\
                a3 = fdot2(vv.z, w[98+(q4)], a3); a3 = fdot2(vv.w, w[99+(q4)], a3);
                DQ(v0, 0) DQ(v1, 4) DQ(v2, 8) DQ(v3, 12)
                DQ(v4, 16) DQ(v5, 20) DQ(v6, 24) DQ(v7, 28)
#undef DQ
                float4 part; part.x = a0; part.y = a1; part.z = a2; part.w = a3;
                *(float4*)&g1[i & 1][ksl1][m1][0] = part;
            }
        }
        __syncthreads();                              // the one barrier
        // ================= phase B (activations / flush) =================
        if (!isL1) {
            const int t = i;
            if (t < S_) {
                const float4 s0 = *(const float4*)&g0[i & 1][0][unit0][0];
                const float4 s1 = *(const float4*)&g0[i & 1][1][unit0][0];
                const float4 s2 = *(const float4*)&g0[i & 1][2][unit0][0];
                const float4 s3 = *(const float4*)&g0[i & 1][3][unit0][0];
                const float ig = sigm((s0.x + s1.x) + (s2.x + s3.x) + bias[0]);
                const float fg = sigm((s0.y + s1.y) + (s2.y + s3.y) + bias[1]);
                const float gc = tanh_((s0.z + s1.z) + (s2.z + s3.z) + bias[2]);
                const float og = sigm((s0.w + s1.w) + (s2.w + s3.w) + bias[3]);
                c = fg * c + ig * gc;
                const float h = og * tanh_(c);
                const u32 pp = packh2(h, dnb1(h));
                if ((j0 & 33) == 0) {                 // even lane, j0<32
                    hb0[wv0][j0 >> 1] = pp;           // private next-A slice
                    if (!(wv0 & 1)) ring[t & 3][unit0 >> 1] = pp;  // for L1
                }
                if (t == S_ - 1 && !(wv0 & 1) && j0 < 32) {
                    out[HH0 + (size_t)b * H_ + unit0] = h;
                    out[HC0 + (size_t)b * H_ + unit0] = c;
                }
            }
        } else {
            const int u = i - 2;
            if (u >= 0) {
                if (ksl1 >= 2) {                      // waves 4-7: activations
                    const float4 s0 = *(const float4*)&g1[i & 1][0][unit1][0];
                    const float4 s1 = *(const float4*)&g1[i & 1][1][unit1][0];
                    const float4 s2 = *(const float4*)&g1[i & 1][2][unit1][0];
                    const float4 s3 = *(const float4*)&g1[i & 1][3][unit1][0];
                    const float ig = sigm((s0.x + s1.x) + (s2.x + s3.x) + bias[0]);
                    const float fg = sigm((s0.y + s1.y) + (s2.y + s3.y) + bias[1]);
                    const float gc = tanh_((s0.z + s1.z) + (s2.z + s3.z) + bias[2]);
                    const float og = sigm((s0.w + s1.w) + (s2.w + s3.w) + bias[3]);
                    c = fg * c + ig * gc;
                    const float h = og * tanh_(c);
                    const u32 pp = packh2(h, dnb1(h));
                    if (!(j1 & 1)) {
                        hb2[wv1][j1 >> 1] = pp;
                        if (!(wv1 & 1)) och[(u >> 5) & 1][(u & 31) * 64 + (unit1 >> 1)] = pp;
                    }
                    if (u == S_ - 1 && !(wv1 & 1)) {
                        out[HH0 + 32768 + (size_t)b * H_ + unit1] = h;
                        out[HC0 + 32768 + (size_t)b * H_ + unit1] = c;
                    }
                } else if ((u & 31) == 0 && u) {      // waves 0-3: h2 flush
                    u32* dst = hbase + (size_t)(u - 32) * 64;
                    const u32* sb = och[((u >> 5) & 1) ^ 1];
                    *(uint4*)(dst + tid * 8)     = *(const uint4*)(sb + tid * 8);
                    *(uint4*)(dst + tid * 8 + 4) = *(const uint4*)(sb + tid * 8 + 4);
                }
            }
        }
    }
    __syncthreads();
    if (tid < 512) {   // final h2 window [2016, 2048), och buffer 1
        u32* dst = hbase + (size_t)(S_ - 32) * 64;
        *(uint4*)(dst + tid * 4) = *(const uint4*)&och[1][tid * 4];
    }
}

// ===================== heads: parallel over (b,s) ===========================
__global__ __launch_bounds__(256) void k_heads(
    const u32* __restrict__ h2p,
    const float* __restrict__ Wr1, const float* __restrict__ br1,
    const float* __restrict__ Wr2, const float* __restrict__ br2,
    const float* __restrict__ Wv1, const float* __restrict__ bv1,
    const float* __restrict__ Wv2, const float* __restrict__ bv2,
    float* __restrict__ out)
{
    __shared__ u32 wr[64 * 64], wv[64 * 64];
    __shared__ float w2r[64], w2v[64], b1r[64], b1v[64];

    const int tid = threadIdx.x;
    for (int i = tid; i < 4096; i += 256) {
        wr[i] = packh2(Wr1[2 * i], Wr1[2 * i + 1]);
        wv[i] = packh2(Wv1[2 * i], Wv1[2 * i + 1]);
    }
    if (tid < 64) {
        w2r[tid] = Wr2[tid]; w2v[tid] = Wv2[tid];
        b1r[tid] = br1[tid]; b1v[tid] = bv1[tid];
    }
    __syncthreads();

    const size_t bs = (size_t)blockIdx.x * 256 + tid;
    u32 hq[64];
    const u32* src = h2p + bs * 64;
#pragma unroll
    for (int j4 = 0; j4 < 16; ++j4) {
        const uint4 v = *(const uint4*)(src + j4 * 4);
        hq[j4 * 4] = v.x; hq[j4 * 4 + 1] = v.y;
        hq[j4 * 4 + 2] = v.z; hq[j4 * 4 + 3] = v.w;
    }
    float ret = br2[0], vol = bv2[0];
    for (int k = 0; k < 64; ++k) {
        float r = b1r[k], v = b1v[k];
#pragma unroll
        for (int j = 0; j < 64; ++j) r = fdot2(hq[j], wr[k * 64 + j], r);
#pragma unroll
        for (int j = 0; j < 64; ++j) v = fdot2(hq[j], wv[k * 64 + j], v);
        r = r > 0.f ? r : 0.01f * r;
        v = v > 0.f ? v : 0.01f * v;
        ret += r * w2r[k];
        vol += v * w2v[k];
    }
    out[RET0 + bs] = ret;
    out[VOL0 + bs] = softplus_(vol);
}

extern "C" void kernel_launch(void* const* d_in, const int* in_sizes, int n_in,
                              void* d_out, int out_size, void* d_ws, size_t ws_size,
                              hipStream_t stream) {
    (void)in_sizes; (void)n_in; (void)out_size; (void)ws_size;
    const float* x    = (const float*)d_in[0];
    const float* Wih0 = (const float*)d_in[1];
    const float* Whh0 = (const float*)d_in[2];
    const float* bih0 = (const float*)d_in[3];
    const float* bhh0 = (const float*)d_in[4];
    const float* Wih1 = (const float*)d_in[5];
    const float* Whh1 = (const float*)d_in[6];
    const float* bih1 = (const float*)d_in[7];
    const float* bhh1 = (const float*)d_in[8];
    const float* Wr1  = (const float*)d_in[9];
    const float* br1  = (const float*)d_in[10];
    const float* Wr2  = (const float*)d_in[11];
    const float* br2  = (const float*)d_in[12];
    const float* Wv1  = (const float*)d_in[13];
    const float* bv1  = (const float*)d_in[14];
    const float* Wv2  = (const float*)d_in[15];
    const float* bv2  = (const float*)d_in[16];
    u32* hws  = (u32*)d_ws;           // h2 pairs [b*S+u][64] (for k_heads)
    float* out = (float*)d_out;

    k_fused<<<B_, 1024, 0, stream>>>(x, Wih0, Whh0, bih0, bhh0,
                                     Wih1, Whh1, bih1, bhh1, hws, out);
    k_heads<<<2048, 256, 0, stream>>>(hws, Wr1, br1, Wr2, br2,
                                      Wv1, bv1, Wv2, bv2, out);
}

// Round 18
// 3609.982 us; speedup vs baseline: 6.6596x; 6.6596x over previous
//
#include <hip/hip_runtime.h>
#include <hip/hip_bf16.h>

#define B_ 256
#define S_ 2048
#define D_ 16
#define H_ 128

typedef unsigned int u32;
typedef _Float16 h2t __attribute__((ext_vector_type(2)));

// ---- output layout (flat f32): returns | volatility | hidden_h | hidden_c
#define RET0 ((size_t)0)
#define VOL0 ((size_t)524288)
#define HH0  ((size_t)1048576)
#define HC0  ((size_t)1114112)

__device__ __forceinline__ float fdot2(u32 a, u32 b, float c) {
    return __builtin_amdgcn_fdot2(__builtin_bit_cast(h2t, a),
                                  __builtin_bit_cast(h2t, b), c, false);
}
__device__ __forceinline__ u32 packh2(float a, float b) {
    h2t h; h[0] = (_Float16)a; h[1] = (_Float16)b;
    return __builtin_bit_cast(u32, h);
}
__device__ __forceinline__ float sigm(float x) {
    return __builtin_amdgcn_rcpf(1.f + __builtin_amdgcn_exp2f(-1.44269504f * x));
}
__device__ __forceinline__ float tanh_(float x) {
    return 2.f * __builtin_amdgcn_rcpf(1.f + __builtin_amdgcn_exp2f(-2.88539008f * x)) - 1.f;
}
__device__ __forceinline__ float softplus_(float x) {
    if (x > 20.f) return x;
    const float e = __builtin_amdgcn_exp2f(1.44269504f * x);
    return 0.69314718f * __builtin_amdgcn_logf(1.f + e);
}
// DPP helpers
__device__ __forceinline__ float dnb1(float a) {   // quad_perm [1,0,3,2]
    return __builtin_bit_cast(float, __builtin_amdgcn_update_dpp(
        0, __builtin_bit_cast(int, a), 0xB1, 0xF, 0xF, true));
}
__device__ __forceinline__ float dxor1(float a) {
    return __builtin_bit_cast(float, __builtin_amdgcn_update_dpp(
        0, __builtin_bit_cast(int, a), 0xB1, 0xF, 0xF, true));
}
__device__ __forceinline__ float dxor2(float a) {  // quad_perm [2,3,0,1]
    return __builtin_bit_cast(float, __builtin_amdgcn_update_dpp(
        0, __builtin_bit_cast(int, a), 0x4E, 0xF, 0xF, true));
}

// ===================== layer 0 (round-14, verbatim — measured best) =========
__global__ __launch_bounds__(512, 2) void k_l0(
    const float* __restrict__ x, const float* __restrict__ Wih,
    const float* __restrict__ Whh, const float* __restrict__ bih,
    const float* __restrict__ bhh, u32* __restrict__ h1out,
    float* __restrict__ out)
{
    __shared__ u32 xp2[2][2048];          // 2 x 256-step x window (16KB)
    __shared__ float gates[2][4][128][4]; // dbuf gate partials (16KB)
    __shared__ u32 hb[8][16];             // per-wave private h1 pair slice
    __shared__ u32 och[2][2048];          // dbuf 32-step staging (16KB)

    const int tid = threadIdx.x, b = blockIdx.x;
    const int ksl = tid >> 7, m = tid & 127;
    const int wv = tid >> 6, j = tid & 63;
    const int unit = (ksl << 5) + (j & 31);

    u32 wx[8], wh[64];
#pragma unroll
    for (int g = 0; g < 4; ++g) {
        const int row = g * H_ + m;
        const float4 fx = *(const float4*)(Wih + row * D_ + ksl * 4);
        wx[g * 2]     = packh2(fx.x, fx.y);
        wx[g * 2 + 1] = packh2(fx.z, fx.w);
        const float4* whr = (const float4*)(Whh + row * H_ + ksl * 32);
#pragma unroll
        for (int q = 0; q < 8; ++q) {
            const float4 f = whr[q];
            wh[g * 16 + 2 * q]     = packh2(f.x, f.y);
            wh[g * 16 + 2 * q + 1] = packh2(f.z, f.w);
        }
    }
    const float bias0 = bih[unit] + bhh[unit];
    const float bias1 = bih[128 + unit] + bhh[128 + unit];
    const float bias2 = bih[256 + unit] + bhh[256 + unit];
    const float bias3 = bih[384 + unit] + bhh[384 + unit];

    const float* xb = x + (size_t)b * S_ * D_;
#pragma unroll
    for (int k = 0; k < 2; ++k) {         // stage x window 0
        const int i = tid + k * 512;
        const float4 v = *(const float4*)(xb + i * 4);
        xp2[0][2 * i]     = packh2(v.x, v.y);
        xp2[0][2 * i + 1] = packh2(v.z, v.w);
    }
    if (tid < 128) ((u32*)hb)[tid] = 0u;
    float c = 0.f;
    __syncthreads();

    for (int t = 0; t < S_; ++t) {
        if ((t & 255) == 0 && t < S_ - 256) {   // prefetch next x window
            const int nw = (t >> 8) + 1;
#pragma unroll
            for (int k = 0; k < 2; ++k) {
                const int i = tid + k * 512;
                const float4 v = *(const float4*)(xb + (size_t)nw * 4096 + i * 4);
                xp2[nw & 1][2 * i]     = packh2(v.x, v.y);
                xp2[nw & 1][2 * i + 1] = packh2(v.z, v.w);
            }
        }
        // ---- A: dots on this wave's private slice
        const uint2 xv = *(const uint2*)&xp2[(t >> 8) & 1][(t & 255) * 8 + ksl * 2];
        const uint4* hq = (const uint4*)hb[wv];
        const uint4 h0 = hq[0], h1 = hq[1], h2 = hq[2], h3 = hq[3];
        float a0 = fdot2(xv.x, wx[0], 0.f); a0 = fdot2(xv.y, wx[1], a0);
        float a1 = fdot2(xv.x, wx[2], 0.f); a1 = fdot2(xv.y, wx[3], a1);
        float a2 = fdot2(xv.x, wx[4], 0.f); a2 = fdot2(xv.y, wx[5], a2);
        float a3 = fdot2(xv.x, wx[6], 0.f); a3 = fdot2(xv.y, wx[7], a3);
#define DG(vv, p)                                                              \
        a0 = fdot2(vv, wh[p], a0);        a1 = fdot2(vv, wh[16 + (p)], a1);    \
        a2 = fdot2(vv, wh[32 + (p)], a2); a3 = fdot2(vv, wh[48 + (p)], a3);
        DG(h0.x, 0) DG(h0.y, 1) DG(h0.z, 2) DG(h0.w, 3)
        DG(h1.x, 4) DG(h1.y, 5) DG(h1.z, 6) DG(h1.w, 7)
        DG(h2.x, 8) DG(h2.y, 9) DG(h2.z, 10) DG(h2.w, 11)
        DG(h3.x, 12) DG(h3.y, 13) DG(h3.z, 14) DG(h3.w, 15)
#undef DG
        float4 part; part.x = a0; part.y = a1; part.z = a2; part.w = a3;
        *(float4*)&gates[t & 1][ksl][m][0] = part;
        __syncthreads();                       // the ONLY barrier per step
        // ---- B (all waves; each owns units [32ksl, 32ksl+32))
        if ((t & 31) == 0 && t) {              // flush previous och window
            u32* dst = h1out + ((size_t)b * S_ + (t - 32)) * 64;
            *(uint4*)(dst + tid * 4) = *(const uint4*)&och[((t >> 5) & 1) ^ 1][tid * 4];
        }
        const float4 s0 = *(const float4*)&gates[t & 1][0][unit][0];
        const float4 s1 = *(const float4*)&gates[t & 1][1][unit][0];
        const float4 s2 = *(const float4*)&gates[t & 1][2][unit][0];
        const float4 s3 = *(const float4*)&gates[t & 1][3][unit][0];
        const float ig = sigm((s0.x + s1.x) + (s2.x + s3.x) + bias0);
        const float fg = sigm((s0.y + s1.y) + (s2.y + s3.y) + bias1);
        const float gc = tanh_((s0.z + s1.z) + (s2.z + s3.z) + bias2);
        const float og = sigm((s0.w + s1.w) + (s2.w + s3.w) + bias3);
        c = fg * c + ig * gc;
        const float h = og * tanh_(c);
        const u32 pp = packh2(h, dnb1(h));
        if ((j & 33) == 0) {                   // j<32 && even
            hb[wv][j >> 1] = pp;               // private slice for next A
            if (!(wv & 1)) och[(t >> 5) & 1][(t & 31) * 64 + (unit >> 1)] = pp;
        }
        if (t == S_ - 1 && !(wv & 1) && j < 32) {
            out[HH0 + (size_t)b * H_ + unit] = h;
            out[HC0 + (size_t)b * H_ + unit] = c;
        }
    }
    __syncthreads();
    {   // final flush: steps [2016, 2048), och buffer 1
        u32* dst = h1out + ((size_t)b * S_ + (S_ - 32)) * 64;
        *(uint4*)(dst + tid * 4) = *(const uint4*)&och[1][tid * 4];
    }
}

// ============ layer 1 + fused heads (round-13 k_l1 + heads in idle waves) ===
// 1024 thr: A: tid = ksl*128+m dots. B: waves 0-1 activate; waves 2-9 compute
// heads for step u-1 (lag 1); thread 640 finalizes step u-2 (lag 2).
// TWO barriers per step (round-13 structure): A-write->B-read, and
// B-write->next-A-read (hp/gates) — round-17 dropped the second one => race.
__global__ __launch_bounds__(1024) void k_l1h(
    const u32* __restrict__ hws,
    const float* __restrict__ Wih, const float* __restrict__ Whh,
    const float* __restrict__ bih, const float* __restrict__ bhh,
    const float* __restrict__ Wr1, const float* __restrict__ br1,
    const float* __restrict__ Wr2, const float* __restrict__ br2,
    const float* __restrict__ Wv1, const float* __restrict__ bv1,
    const float* __restrict__ Wv2, const float* __restrict__ bv2,
    float* __restrict__ out)
{
    __shared__ u32 h1w[64 * 80];       // 64-step h1 window, padded (20KB)
    __shared__ float gates[8][128][4]; // gate partials (16KB)
    __shared__ u32 hp[2][80];          // h2 state dbuf, padded
    __shared__ u32 whd[8704];          // head W1 pairs, stride 68 (34KB)
    __shared__ float redbuf[2][8];     // head per-wave partials (lag dbuf)
    __shared__ float rvr[S_], rvv[S_]; // returns/vol staging (16KB)

    const int tid = threadIdx.x, b = blockIdx.x;
    const int ksl = tid >> 7, m = tid & 127;

    u32 w[64];
    const float* Wsel = (ksl < 4) ? Wih : Whh;
    const int colb = (ksl & 3) * 32;
#pragma unroll
    for (int g = 0; g < 4; ++g) {
        const int row = g * H_ + m;
        const float4* wr_ = (const float4*)(Wsel + row * H_ + colb);
#pragma unroll
        for (int q = 0; q < 8; ++q) {
            const float4 f = wr_[q];
            w[g * 16 + 2 * q]     = packh2(f.x, f.y);
            w[g * 16 + 2 * q + 1] = packh2(f.z, f.w);
        }
    }
    float bias[4], c = 0.f;
    if (tid < 128) {
#pragma unroll
        for (int g = 0; g < 4; ++g) bias[g] = bih[g * H_ + tid] + bhh[g * H_ + tid];
    }
    // head-thread constants (waves 2-9: tid in [128, 640))
    const int ht = tid - 128;
    const int head = (ht >> 8) & 1;
    const int wk = (ht >> 6) & 3;
    const int hk = wk * 16 + ((ht >> 2) & 15);
    const int hq = ht & 3;
    float b1k = 0.f, w2k = 0.f;
    if (tid >= 128 && tid < 640) {
        b1k = (head ? bv1 : br1)[hk];
        w2k = (head ? Wv2 : Wr2)[hk];
    }
    float br2v = 0.f, bv2v = 0.f;
    if (tid == 640) { br2v = br2[0]; bv2v = bv2[0]; }
    // head weights -> LDS (i = k*64 + p -> W1 elems i*2, i*2+1)
    for (int i = tid; i < 4096; i += 1024) {
        const int kq = i >> 6, p = i & 63;
        whd[kq * 68 + p]        = packh2(Wr1[i * 2], Wr1[i * 2 + 1]);
        whd[4352 + kq * 68 + p] = packh2(Wv1[i * 2], Wv1[i * 2 + 1]);
    }
    if (tid < 160) ((u32*)hp)[tid] = 0u;
    __syncthreads();

    const u32* hbase = hws + (size_t)b * S_ * 64;
    for (int u = 0; u < S_; ++u) {
        if ((u & 63) == 0) {                     // stage 64-step h1 window
            const uint4 v = *(const uint4*)(hbase + (size_t)u * 64 + tid * 4);
            const int st = tid >> 4, p4 = tid & 15;
            *(uint4*)(&h1w[st * 80 + (p4 >> 2) * 20 + (p4 & 3) * 4]) = v;
            __syncthreads();
        }
        // ---- phase A (round-13)
        const u32* sel = (ksl < 4) ? &h1w[(u & 63) * 80 + ksl * 20]
                                   : &hp[(u + 1) & 1][(ksl - 4) * 20];
        float a0 = 0.f, a1 = 0.f, a2 = 0.f, a3 = 0.f;
#pragma unroll
        for (int p = 0; p < 4; ++p) {
            const uint4 v = *(const uint4*)(sel + p * 4);
            a0 = fdot2(v.x, w[4 * p], a0);      a0 = fdot2(v.y, w[4 * p + 1], a0);
            a0 = fdot2(v.z, w[4 * p + 2], a0);  a0 = fdot2(v.w, w[4 * p + 3], a0);
            a1 = fdot2(v.x, w[16 + 4 * p], a1); a1 = fdot2(v.y, w[17 + 4 * p], a1);
            a1 = fdot2(v.z, w[18 + 4 * p], a1); a1 = fdot2(v.w, w[19 + 4 * p], a1);
            a2 = fdot2(v.x, w[32 + 4 * p], a2); a2 = fdot2(v.y, w[33 + 4 * p], a2);
            a2 = fdot2(v.z, w[34 + 4 * p], a2); a2 = fdot2(v.w, w[35 + 4 * p], a2);
            a3 = fdot2(v.x, w[48 + 4 * p], a3); a3 = fdot2(v.y, w[49 + 4 * p], a3);
            a3 = fdot2(v.z, w[50 + 4 * p], a3); a3 = fdot2(v.w, w[51 + 4 * p], a3);
        }
        float4 part; part.x = a0; part.y = a1; part.z = a2; part.w = a3;
        *(float4*)&gates[ksl][m][0] = part;
        __syncthreads();                         // barrier 1: A-write -> B-read
        // ---- phase B
        if (tid < 128) {                         // waves 0-1: activations
            float4 s = *(const float4*)&gates[0][tid][0];
#pragma unroll
            for (int k = 1; k < 8; ++k) {
                const float4 p = *(const float4*)&gates[k][tid][0];
                s.x += p.x; s.y += p.y; s.z += p.z; s.w += p.w;
            }
            const float ig = sigm(s.x + bias[0]);
            const float fg = sigm(s.y + bias[1]);
            const float gc = tanh_(s.z + bias[2]);
            const float og = sigm(s.w + bias[3]);
            c = fg * c + ig * gc;
            const float hv = og * tanh_(c);
            const u32 pp = packh2(hv, dnb1(hv));
            if (!(tid & 1)) {
                const int p2 = tid >> 1;
                hp[u & 1][(p2 >> 4) * 20 + (p2 & 15)] = pp;
            }
            if (u == S_ - 1) {
                out[HH0 + 32768 + (size_t)b * H_ + tid] = hv;
                out[HC0 + 32768 + (size_t)b * H_ + tid] = c;
            }
        } else if (tid < 640) {                  // waves 2-9: heads step u-1
            if (u >= 1) {
                const u32* hsrc = &hp[(u + 1) & 1][hq * 20];
                const uint4 y0 = *(const uint4*)(hsrc);
                const uint4 y1 = *(const uint4*)(hsrc + 4);
                const uint4 y2 = *(const uint4*)(hsrc + 8);
                const uint4 y3 = *(const uint4*)(hsrc + 12);
                const u32* wp = &whd[head * 4352 + hk * 68 + hq * 16];
                const uint4 w0 = *(const uint4*)(wp);
                const uint4 w1 = *(const uint4*)(wp + 4);
                const uint4 w2_ = *(const uint4*)(wp + 8);
                const uint4 w3 = *(const uint4*)(wp + 12);
                float d = 0.f;
                d = fdot2(y0.x, w0.x, d); d = fdot2(y0.y, w0.y, d);
                d = fdot2(y0.z, w0.z, d); d = fdot2(y0.w, w0.w, d);
                d = fdot2(y1.x, w1.x, d); d = fdot2(y1.y, w1.y, d);
                d = fdot2(y1.z, w1.z, d); d = fdot2(y1.w, w1.w, d);
                d = fdot2(y2.x, w2_.x, d); d = fdot2(y2.y, w2_.y, d);
                d = fdot2(y2.z, w2_.z, d); d = fdot2(y2.w, w2_.w, d);
                d = fdot2(y3.x, w3.x, d); d = fdot2(y3.y, w3.y, d);
                d = fdot2(y3.z, w3.z, d); d = fdot2(y3.w, w3.w, d);
                d += dxor1(d); d += dxor2(d);    // quad sum over hq
                float val = 0.f;
                if (hq == 0) {
                    const float dd = d + b1k;
                    val = (dd > 0.f ? dd : 0.01f * dd) * w2k;
                }
                val += __shfl_xor(val, 4);  val += __shfl_xor(val, 8);
                val += __shfl_xor(val, 16); val += __shfl_xor(val, 32);
                if ((tid & 63) == 0) redbuf[(u - 1) & 1][head * 4 + wk] = val;
            }
        } else if (tid == 640) {                 // finalize step u-2
            if (u >= 2) {
                const float* rb = redbuf[u & 1];
                rvr[u - 2] = rb[0] + rb[1] + rb[2] + rb[3] + br2v;
                rvv[u - 2] = softplus_(rb[4] + rb[5] + rb[6] + rb[7] + bv2v);
            }
        }
        __syncthreads();                         // barrier 2: B-write -> next A
    }
    // ---- epilogue: heads for step S-1 (hp[1]); finalize S-2 concurrently
    if (tid >= 128 && tid < 640) {
        const u32* hsrc = &hp[1][hq * 20];       // (S-1)&1 == 1
        const uint4 y0 = *(const uint4*)(hsrc);
        const uint4 y1 = *(const uint4*)(hsrc + 4);
        const uint4 y2 = *(const uint4*)(hsrc + 8);
        const uint4 y3 = *(const uint4*)(hsrc + 12);
        const u32* wp = &whd[head * 4352 + hk * 68 + hq * 16];
        const uint4 w0 = *(const uint4*)(wp);
        const uint4 w1 = *(const uint4*)(wp + 4);
        const uint4 w2_ = *(const uint4*)(wp + 8);
        const uint4 w3 = *(const uint4*)(wp + 12);
        float d = 0.f;
        d = fdot2(y0.x, w0.x, d); d = fdot2(y0.y, w0.y, d);
        d = fdot2(y0.z, w0.z, d); d = fdot2(y0.w, w0.w, d);
        d = fdot2(y1.x, w1.x, d); d = fdot2(y1.y, w1.y, d);
        d = fdot2(y1.z, w1.z, d); d = fdot2(y1.w, w1.w, d);
        d = fdot2(y2.x, w2_.x, d); d = fdot2(y2.y, w2_.y, d);
        d = fdot2(y2.z, w2_.z, d); d = fdot2(y2.w, w2_.w, d);
        d = fdot2(y3.x, w3.x, d); d = fdot2(y3.y, w3.y, d);
        d = fdot2(y3.z, w3.z, d); d = fdot2(y3.w, w3.w, d);
        d += dxor1(d); d += dxor2(d);
        float val = 0.f;
        if (hq == 0) {
            const float dd = d + b1k;
            val = (dd > 0.f ? dd : 0.01f * dd) * w2k;
        }
        val += __shfl_xor(val, 4);  val += __shfl_xor(val, 8);
        val += __shfl_xor(val, 16); val += __shfl_xor(val, 32);
        if ((tid & 63) == 0) redbuf[1][head * 4 + wk] = val;
    } else if (tid == 640) {                     // step S-2: redbuf[0]
        const float* rb = redbuf[0];
        rvr[S_ - 2] = rb[0] + rb[1] + rb[2] + rb[3] + br2v;
        rvv[S_ - 2] = softplus_(rb[4] + rb[5] + rb[6] + rb[7] + bv2v);
    }
    __syncthreads();
    if (tid == 640) {                            // step S-1: redbuf[1]
        const float* rb = redbuf[1];
        rvr[S_ - 1] = rb[0] + rb[1] + rb[2] + rb[3] + br2v;
        rvv[S_ - 1] = softplus_(rb[4] + rb[5] + rb[6] + rb[7] + bv2v);
    }
    __syncthreads();
    // ---- bulk output flush
    for (int s = tid; s < S_; s += 1024) {
        out[RET0 + (size_t)b * S_ + s] = rvr[s];
        out[VOL0 + (size_t)b * S_ + s] = rvv[s];
    }
}

extern "C" void kernel_launch(void* const* d_in, const int* in_sizes, int n_in,
                              void* d_out, int out_size, void* d_ws, size_t ws_size,
                              hipStream_t stream) {
    (void)in_sizes; (void)n_in; (void)out_size; (void)ws_size;
    const float* x    = (const float*)d_in[0];
    const float* Wih0 = (const float*)d_in[1];
    const float* Whh0 = (const float*)d_in[2];
    const float* bih0 = (const float*)d_in[3];
    const float* bhh0 = (const float*)d_in[4];
    const float* Wih1 = (const float*)d_in[5];
    const float* Whh1 = (const float*)d_in[6];
    const float* bih1 = (const float*)d_in[7];
    const float* bhh1 = (const float*)d_in[8];
    const float* Wr1  = (const float*)d_in[9];
    const float* br1  = (const float*)d_in[10];
    const float* Wr2  = (const float*)d_in[11];
    const float* br2  = (const float*)d_in[12];
    const float* Wv1  = (const float*)d_in[13];
    const float* bv1  = (const float*)d_in[14];
    const float* Wv2  = (const float*)d_in[15];
    const float* bv2  = (const float*)d_in[16];
    u32* hws  = (u32*)d_ws;           // 134 MB: h1 pairs [b*S+t][64]
    float* out = (float*)d_out;

    k_l0<<<B_, 512, 0, stream>>>(x, Wih0, Whh0, bih0, bhh0, hws, out);
    k_l1h<<<B_, 1024, 0, stream>>>(hws, Wih1, Whh1, bih1, bhh1,
                                   Wr1, br1, Wr2, br2, Wv1, bv1, Wv2, bv2, out);
}

// Round 19
// 3360.997 us; speedup vs baseline: 7.1530x; 1.0741x over previous
//
#include <hip/hip_runtime.h>
#include <hip/hip_bf16.h>

#define B_ 256
#define S_ 2048
#define D_ 16
#define H_ 128

typedef unsigned int u32;
typedef _Float16 h2t __attribute__((ext_vector_type(2)));

// ---- output layout (flat f32): returns | volatility | hidden_h | hidden_c
#define RET0 ((size_t)0)
#define VOL0 ((size_t)524288)
#define HH0  ((size_t)1048576)
#define HC0  ((size_t)1114112)

__device__ __forceinline__ float fdot2(u32 a, u32 b, float c) {
    return __builtin_amdgcn_fdot2(__builtin_bit_cast(h2t, a),
                                  __builtin_bit_cast(h2t, b), c, false);
}
__device__ __forceinline__ u32 packh2(float a, float b) {
    h2t h; h[0] = (_Float16)a; h[1] = (_Float16)b;
    return __builtin_bit_cast(u32, h);
}
__device__ __forceinline__ float sigm(float x) {
    return __builtin_amdgcn_rcpf(1.f + __builtin_amdgcn_exp2f(-1.44269504f * x));
}
__device__ __forceinline__ float tanh_(float x) {
    return 2.f * __builtin_amdgcn_rcpf(1.f + __builtin_amdgcn_exp2f(-2.88539008f * x)) - 1.f;
}
__device__ __forceinline__ float softplus_(float x) {
    if (x > 20.f) return x;
    const float e = __builtin_amdgcn_exp2f(1.44269504f * x);
    return 0.69314718f * __builtin_amdgcn_logf(1.f + e);
}
// DPP lane^1 neighbor (quad_perm [1,0,3,2])
__device__ __forceinline__ float dnb1(float a) {
    return __builtin_bit_cast(float, __builtin_amdgcn_update_dpp(
        0, __builtin_bit_cast(int, a), 0xB1, 0xF, 0xF, true));
}

// ===================== layer 0 (round-14 structure — measured best ~1050us) =
__global__ __launch_bounds__(512, 2) void k_l0(
    const float* __restrict__ x, const float* __restrict__ Wih,
    const float* __restrict__ Whh, const float* __restrict__ bih,
    const float* __restrict__ bhh, u32* __restrict__ h1out,
    float* __restrict__ out)
{
    __shared__ u32 xp2[2][2048];          // 2 x 256-step x window (16KB)
    __shared__ float gates[2][4][128][4]; // dbuf gate partials (16KB)
    __shared__ u32 hb[8][16];             // per-wave private h1 pair slice
    __shared__ u32 och[2][2048];          // dbuf 32-step staging (16KB)

    const int tid = threadIdx.x, b = blockIdx.x;
    const int ksl = tid >> 7, m = tid & 127;
    const int wv = tid >> 6, j = tid & 63;
    const int unit = (ksl << 5) + (j & 31);

    u32 wx[8], wh[64];
#pragma unroll
    for (int g = 0; g < 4; ++g) {
        const int row = g * H_ + m;
        const float4 fx = *(const float4*)(Wih + row * D_ + ksl * 4);
        wx[g * 2]     = packh2(fx.x, fx.y);
        wx[g * 2 + 1] = packh2(fx.z, fx.w);
        const float4* whr = (const float4*)(Whh + row * H_ + ksl * 32);
#pragma unroll
        for (int q = 0; q < 8; ++q) {
            const float4 f = whr[q];
            wh[g * 16 + 2 * q]     = packh2(f.x, f.y);
            wh[g * 16 + 2 * q + 1] = packh2(f.z, f.w);
        }
    }
    const float bias0 = bih[unit] + bhh[unit];
    const float bias1 = bih[128 + unit] + bhh[128 + unit];
    const float bias2 = bih[256 + unit] + bhh[256 + unit];
    const float bias3 = bih[384 + unit] + bhh[384 + unit];

    const float* xb = x + (size_t)b * S_ * D_;
#pragma unroll
    for (int k = 0; k < 2; ++k) {         // stage x window 0
        const int i = tid + k * 512;
        const float4 v = *(const float4*)(xb + i * 4);
        xp2[0][2 * i]     = packh2(v.x, v.y);
        xp2[0][2 * i + 1] = packh2(v.z, v.w);
    }
    if (tid < 128) ((u32*)hb)[tid] = 0u;
    float c = 0.f;
    __syncthreads();

    for (int t = 0; t < S_; ++t) {
        if ((t & 255) == 0 && t < S_ - 256) {   // prefetch next x window
            const int nw = (t >> 8) + 1;
#pragma unroll
            for (int k = 0; k < 2; ++k) {
                const int i = tid + k * 512;
                const float4 v = *(const float4*)(xb + (size_t)nw * 4096 + i * 4);
                xp2[nw & 1][2 * i]     = packh2(v.x, v.y);
                xp2[nw & 1][2 * i + 1] = packh2(v.z, v.w);
            }
        }
        // ---- A: dots on this wave's private slice
        const uint2 xv = *(const uint2*)&xp2[(t >> 8) & 1][(t & 255) * 8 + ksl * 2];
        const uint4* hq = (const uint4*)hb[wv];
        const uint4 h0 = hq[0], h1 = hq[1], h2 = hq[2], h3 = hq[3];
        float a0 = fdot2(xv.x, wx[0], 0.f); a0 = fdot2(xv.y, wx[1], a0);
        float a1 = fdot2(xv.x, wx[2], 0.f); a1 = fdot2(xv.y, wx[3], a1);
        float a2 = fdot2(xv.x, wx[4], 0.f); a2 = fdot2(xv.y, wx[5], a2);
        float a3 = fdot2(xv.x, wx[6], 0.f); a3 = fdot2(xv.y, wx[7], a3);
#define DG(vv, p)                                                              \
        a0 = fdot2(vv, wh[p], a0);        a1 = fdot2(vv, wh[16 + (p)], a1);    \
        a2 = fdot2(vv, wh[32 + (p)], a2); a3 = fdot2(vv, wh[48 + (p)], a3);
        DG(h0.x, 0) DG(h0.y, 1) DG(h0.z, 2) DG(h0.w, 3)
        DG(h1.x, 4) DG(h1.y, 5) DG(h1.z, 6) DG(h1.w, 7)
        DG(h2.x, 8) DG(h2.y, 9) DG(h2.z, 10) DG(h2.w, 11)
        DG(h3.x, 12) DG(h3.y, 13) DG(h3.z, 14) DG(h3.w, 15)
#undef DG
        float4 part; part.x = a0; part.y = a1; part.z = a2; part.w = a3;
        *(float4*)&gates[t & 1][ksl][m][0] = part;
        __syncthreads();                       // the ONLY barrier per step
        // ---- B (all waves; each owns units [32ksl, 32ksl+32))
        if ((t & 31) == 0 && t) {              // flush previous och window
            u32* dst = h1out + ((size_t)b * S_ + (t - 32)) * 64;
            *(uint4*)(dst + tid * 4) = *(const uint4*)&och[((t >> 5) & 1) ^ 1][tid * 4];
        }
        const float4 s0 = *(const float4*)&gates[t & 1][0][unit][0];
        const float4 s1 = *(const float4*)&gates[t & 1][1][unit][0];
        const float4 s2 = *(const float4*)&gates[t & 1][2][unit][0];
        const float4 s3 = *(const float4*)&gates[t & 1][3][unit][0];
        const float ig = sigm((s0.x + s1.x) + (s2.x + s3.x) + bias0);
        const float fg = sigm((s0.y + s1.y) + (s2.y + s3.y) + bias1);
        const float gc = tanh_((s0.z + s1.z) + (s2.z + s3.z) + bias2);
        const float og = sigm((s0.w + s1.w) + (s2.w + s3.w) + bias3);
        c = fg * c + ig * gc;
        const float h = og * tanh_(c);
        const u32 pp = packh2(h, dnb1(h));
        if ((j & 33) == 0) {                   // j<32 && even
            hb[wv][j >> 1] = pp;               // private slice for next A
            if (!(wv & 1)) och[(t >> 5) & 1][(t & 31) * 64 + (unit >> 1)] = pp;
        }
        if (t == S_ - 1 && !(wv & 1) && j < 32) {
            out[HH0 + (size_t)b * H_ + unit] = h;
            out[HC0 + (size_t)b * H_ + unit] = c;
        }
    }
    __syncthreads();
    {   // final flush: steps [2016, 2048), och buffer 1
        u32* dst = h1out + ((size_t)b * S_ + (S_ - 32)) * 64;
        *(uint4*)(dst + tid * 4) = *(const uint4*)&och[1][tid * 4];
    }
}

// ===================== layer 1 (round-13 structure — measured best ~2040us) =
// 1024 thr: tid = ksl*128 + m. K-concat [h1|h2]: ksl<4 -> h1 window, ksl>=4 ->
// h2 state. Two barriers/step. h2 overwrites consumed h1 rows in ws.
__global__
__attribute__((amdgpu_waves_per_eu(4, 4)))
__launch_bounds__(1024) void k_l1(
    u32* __restrict__ hws,
    const float* __restrict__ Wih, const float* __restrict__ Whh,
    const float* __restrict__ bih, const float* __restrict__ bhh,
    float* __restrict__ out)
{
    __shared__ u32 h1w[64 * 80];       // 64-step h1 window, padded (20KB)
    __shared__ float gates[8][128][4]; // gate partials (16KB)
    __shared__ u32 hp[2][80];          // h2 state dbuf, padded
    __shared__ u32 och[2048];          // 32-step h2 staging (8KB)

    const int tid = threadIdx.x, b = blockIdx.x;
    const int ksl = tid >> 7, m = tid & 127;

    u32 w[64];
    const float* Wsel = (ksl < 4) ? Wih : Whh;
    const int colb = (ksl & 3) * 32;
#pragma unroll
    for (int g = 0; g < 4; ++g) {
        const int row = g * H_ + m;
        const float4* wr_ = (const float4*)(Wsel + row * H_ + colb);
#pragma unroll
        for (int q = 0; q < 8; ++q) {
            const float4 f = wr_[q];
            w[g * 16 + 2 * q]     = packh2(f.x, f.y);
            w[g * 16 + 2 * q + 1] = packh2(f.z, f.w);
        }
    }
    float bias[4], c = 0.f;
    if (tid < 128) {
#pragma unroll
        for (int g = 0; g < 4; ++g) bias[g] = bih[g * H_ + tid] + bhh[g * H_ + tid];
    }
    if (tid < 160) ((u32*)hp)[tid] = 0u;
    __syncthreads();

    u32* hbase = hws + (size_t)b * S_ * 64;
    for (int u = 0; u < S_; ++u) {
        if ((u & 63) == 0) {                     // stage 64-step h1 window
            const uint4 v = *(const uint4*)(hbase + (size_t)u * 64 + tid * 4);
            const int st = tid >> 4, p4 = tid & 15;
            *(uint4*)(&h1w[st * 80 + (p4 >> 2) * 20 + (p4 & 3) * 4]) = v;
            __syncthreads();
        }
        // ---- phase A
        const u32* sel = (ksl < 4) ? &h1w[(u & 63) * 80 + ksl * 20]
                                   : &hp[(u + 1) & 1][(ksl - 4) * 20];
        float a0 = 0.f, a1 = 0.f, a2 = 0.f, a3 = 0.f;
#pragma unroll
        for (int p = 0; p < 4; ++p) {
            const uint4 v = *(const uint4*)(sel + p * 4);
            a0 = fdot2(v.x, w[4 * p], a0);      a0 = fdot2(v.y, w[4 * p + 1], a0);
            a0 = fdot2(v.z, w[4 * p + 2], a0);  a0 = fdot2(v.w, w[4 * p + 3], a0);
            a1 = fdot2(v.x, w[16 + 4 * p], a1); a1 = fdot2(v.y, w[17 + 4 * p], a1);
            a1 = fdot2(v.z, w[18 + 4 * p], a1); a1 = fdot2(v.w, w[19 + 4 * p], a1);
            a2 = fdot2(v.x, w[32 + 4 * p], a2); a2 = fdot2(v.y, w[33 + 4 * p], a2);
            a2 = fdot2(v.z, w[34 + 4 * p], a2); a2 = fdot2(v.w, w[35 + 4 * p], a2);
            a3 = fdot2(v.x, w[48 + 4 * p], a3); a3 = fdot2(v.y, w[49 + 4 * p], a3);
            a3 = fdot2(v.z, w[50 + 4 * p], a3); a3 = fdot2(v.w, w[51 + 4 * p], a3);
        }
        float4 part; part.x = a0; part.y = a1; part.z = a2; part.w = a3;
        *(float4*)&gates[ksl][m][0] = part;
        __syncthreads();                         // barrier 1: A-write -> B-read
        // ---- phase B
        if (tid < 128) {
            float4 s = *(const float4*)&gates[0][tid][0];
#pragma unroll
            for (int k = 1; k < 8; ++k) {
                const float4 p = *(const float4*)&gates[k][tid][0];
                s.x += p.x; s.y += p.y; s.z += p.z; s.w += p.w;
            }
            const float ig = sigm(s.x + bias[0]);
            const float fg = sigm(s.y + bias[1]);
            const float gc = tanh_(s.z + bias[2]);
            const float og = sigm(s.w + bias[3]);
            c = fg * c + ig * gc;
            const float hv = og * tanh_(c);
            const u32 pp = packh2(hv, dnb1(hv));
            if (!(tid & 1)) {
                const int p2 = tid >> 1;
                hp[u & 1][(p2 >> 4) * 20 + (p2 & 15)] = pp;
                och[(u & 31) * 64 + p2] = pp;
            }
            if (u == S_ - 1) {
                out[HH0 + 32768 + (size_t)b * H_ + tid] = hv;
                out[HC0 + 32768 + (size_t)b * H_ + tid] = c;
            }
        }
        __syncthreads();                         // barrier 2: B-write -> next A
        if ((u & 31) == 31) {                    // flush h2 over consumed h1
            if (tid < 512) {
                u32* dst = hbase + (size_t)(u - 31) * 64;
                *(uint4*)(dst + tid * 4) = *(const uint4*)(&och[tid * 4]);
            }
            __syncthreads();
        }
    }
}

// ===================== heads: parallel over (b,s) ===========================
__global__ __launch_bounds__(256) void k_heads(
    const u32* __restrict__ h2p,
    const float* __restrict__ Wr1, const float* __restrict__ br1,
    const float* __restrict__ Wr2, const float* __restrict__ br2,
    const float* __restrict__ Wv1, const float* __restrict__ bv1,
    const float* __restrict__ Wv2, const float* __restrict__ bv2,
    float* __restrict__ out)
{
    __shared__ u32 wr[64 * 64], wv[64 * 64];
    __shared__ float w2r[64], w2v[64], b1r[64], b1v[64];

    const int tid = threadIdx.x;
    for (int i = tid; i < 4096; i += 256) {
        wr[i] = packh2(Wr1[2 * i], Wr1[2 * i + 1]);
        wv[i] = packh2(Wv1[2 * i], Wv1[2 * i + 1]);
    }
    if (tid < 64) {
        w2r[tid] = Wr2[tid]; w2v[tid] = Wv2[tid];
        b1r[tid] = br1[tid]; b1v[tid] = bv1[tid];
    }
    __syncthreads();

    const size_t bs = (size_t)blockIdx.x * 256 + tid;
    u32 hq[64];
    const u32* src = h2p + bs * 64;
#pragma unroll
    for (int j4 = 0; j4 < 16; ++j4) {
        const uint4 v = *(const uint4*)(src + j4 * 4);
        hq[j4 * 4] = v.x; hq[j4 * 4 + 1] = v.y;
        hq[j4 * 4 + 2] = v.z; hq[j4 * 4 + 3] = v.w;
    }
    float ret = br2[0], vol = bv2[0];
    for (int k = 0; k < 64; ++k) {
        float r = b1r[k], v = b1v[k];
#pragma unroll
        for (int j = 0; j < 64; ++j) r = fdot2(hq[j], wr[k * 64 + j], r);
#pragma unroll
        for (int j = 0; j < 64; ++j) v = fdot2(hq[j], wv[k * 64 + j], v);
        r = r > 0.f ? r : 0.01f * r;
        v = v > 0.f ? v : 0.01f * v;
        ret += r * w2r[k];
        vol += v * w2v[k];
    }
    out[RET0 + bs] = ret;
    out[VOL0 + bs] = softplus_(vol);
}

extern "C" void kernel_launch(void* const* d_in, const int* in_sizes, int n_in,
                              void* d_out, int out_size, void* d_ws, size_t ws_size,
                              hipStream_t stream) {
    (void)in_sizes; (void)n_in; (void)out_size; (void)ws_size;
    const float* x    = (const float*)d_in[0];
    const float* Wih0 = (const float*)d_in[1];
    const float* Whh0 = (const float*)d_in[2];
    const float* bih0 = (const float*)d_in[3];
    const float* bhh0 = (const float*)d_in[4];
    const float* Wih1 = (const float*)d_in[5];
    const float* Whh1 = (const float*)d_in[6];
    const float* bih1 = (const float*)d_in[7];
    const float* bhh1 = (const float*)d_in[8];
    const float* Wr1  = (const float*)d_in[9];
    const float* br1  = (const float*)d_in[10];
    const float* Wr2  = (const float*)d_in[11];
    const float* br2  = (const float*)d_in[12];
    const float* Wv1  = (const float*)d_in[13];
    const float* bv1  = (const float*)d_in[14];
    const float* Wv2  = (const float*)d_in[15];
    const float* bv2  = (const float*)d_in[16];
    u32* hws  = (u32*)d_ws;           // 134 MB: h1 pairs, then h2 in-place
    float* out = (float*)d_out;

    k_l0<<<B_, 512, 0, stream>>>(x, Wih0, Whh0, bih0, bhh0, hws, out);
    k_l1<<<B_, 1024, 0, stream>>>(hws, Wih1, Whh1, bih1, bhh1, out);
    k_heads<<<2048, 256, 0, stream>>>(hws, Wr1, br1, Wr2, br2,
                                      Wv1, bv1, Wv2, bv2, out);
}